// Round 1
// 1061.281 us; speedup vs baseline: 1.0527x; 1.0527x over previous
//
#include <hip/hip_runtime.h>
#include <hip/hip_bf16.h>

typedef __attribute__((ext_vector_type(8))) short short8;
typedef __attribute__((ext_vector_type(4))) float floatx4;
typedef __attribute__((ext_vector_type(4))) unsigned short ushortx4;

__device__ __forceinline__ float bf2f(unsigned short u) {
    union { float f; unsigned int i; } v; v.i = ((unsigned int)u) << 16; return v.f;
}
__device__ __forceinline__ unsigned short f2bf(float f) {
    union { float f; unsigned int i; } v; v.f = f;
    unsigned int r = v.i + 0x7fffu + ((v.i >> 16) & 1u);
    return (unsigned short)(r >> 16);
}

// ---------------------------------------------------------------------------
// CSR build: degree histogram -> chunked block scan -> scatter.
// ---------------------------------------------------------------------------
__global__ void deg_count(const int* __restrict__ dst, int* __restrict__ deg, int E) {
    int i = blockIdx.x * 256 + threadIdx.x;
    if (i < E) atomicAdd(&deg[dst[i]], 1);
}

__global__ __launch_bounds__(1024) void scan_rowptr(const int* __restrict__ deg,
                                                    int* __restrict__ rowptr,
                                                    int* __restrict__ cursor, int N) {
    const int CH = 20;  // 1024*20 = 20480 >= N
    __shared__ int buf[1024];
    int t = threadIdx.x;
    int base = t * CH;
    int local[CH];
    int tot = 0;
#pragma unroll
    for (int k = 0; k < CH; ++k) {
        int i = base + k;
        int v = (i < N) ? deg[i] : 0;
        local[k] = tot;
        tot += v;
    }
    buf[t] = tot;
    __syncthreads();
    for (int off = 1; off < 1024; off <<= 1) {
        int x = (t >= off) ? buf[t - off] : 0;
        __syncthreads();
        buf[t] += x;
        __syncthreads();
    }
    int excl = buf[t] - tot;
#pragma unroll
    for (int k = 0; k < CH; ++k) {
        int i = base + k;
        if (i < N) { rowptr[i] = excl + local[k]; cursor[i] = excl + local[k]; }
    }
    if (t == 1023) rowptr[N] = buf[1023];
}

__global__ void scatter_edges(const int* __restrict__ src, const int* __restrict__ dst,
                              int* __restrict__ cursor, int* __restrict__ eix,
                              int* __restrict__ sx, int E) {
    int i = blockIdx.x * 256 + threadIdx.x;
    if (i >= E) return;
    int d = dst[i];
    int pos = atomicAdd(&cursor[d], 1);
    eix[pos] = i;
    sx[pos] = src[i];
}

// ---------------------------------------------------------------------------
// Weight pre-transpose + bf16 convert: Wt[slot][n*128+k] = bf16(W[slot][k*128+n])
// ---------------------------------------------------------------------------
__global__ void transpose_w(const float* __restrict__ Wh,
                            const float* __restrict__ We,
                            const float* __restrict__ Aw,
                            const float* __restrict__ Bw,
                            const float* __restrict__ Cw,
                            const float* __restrict__ Dw,
                            const float* __restrict__ Ew,
                            unsigned short* __restrict__ Wt) {
    int i = blockIdx.x * 256 + threadIdx.x;
    const int total = 22 * 16384;
    if (i >= total) return;
    int slot = i >> 14;
    int r = i & 16383;
    int n = r >> 7;
    int k = r & 127;
    const float* srcp;
    if (slot == 0) srcp = Wh;
    else if (slot == 1) srcp = We;
    else {
        int t = slot - 2;
        int l = t / 5, w = t % 5;
        const float* bases[5] = {Aw, Bw, Cw, Dw, Ew};
        srcp = bases[w] + l * 16384;
    }
    Wt[i] = f2bf(srcp[k * 128 + n]);
}

// ---------------------------------------------------------------------------
// Streaming GEMM: C[M,128] = A[M,128]@W + bias.
// Column-split: wave wv owns cols [wv*32, wv*32+32) -> B-frags are only
// 8 x short8 = 32 VGPRs (no spill). Swapped-operand MFMA (b as A-operand)
// makes each lane hold 4 CONTIGUOUS output cols of one row -> 8B/16B stores.
// Grid-stride over 16-row strips with double-buffered A prefetch.
// ---------------------------------------------------------------------------
template <int IN_BF16, int OUT_BF16, int GATHER>
__global__ __launch_bounds__(256) void gemm128(const void* __restrict__ Ain,
                                               const int* __restrict__ ridx,
                                               const unsigned short* __restrict__ Wt,
                                               const float* __restrict__ bias,
                                               void* __restrict__ Cout, int nStrips) {
    const int lane = threadIdx.x & 63;
    const int wv = threadIdx.x >> 6;   // wave -> nt blocks {2wv, 2wv+1}
    const int m16 = lane & 15;
    const int kg = lane >> 4;

    short8 b[4][2];
#pragma unroll
    for (int j = 0; j < 2; ++j)
#pragma unroll
        for (int ks = 0; ks < 4; ++ks)
            b[ks][j] = *(const short8*)(Wt + ((wv * 2 + j) * 16 + m16) * 128 + ks * 32 + kg * 8);

    floatx4 bv[2];
#pragma unroll
    for (int j = 0; j < 2; ++j)
        bv[j] = *(const floatx4*)(bias + (wv * 2 + j) * 16 + kg * 4);

    const float* Af = (const float*)Ain;
    const unsigned short* Ab16 = (const unsigned short*)Ain;

    const int stride = gridDim.x;
    int s0 = blockIdx.x;
    if (s0 >= nStrips) return;

    auto loadA = [&](int s, short8* a) {
        int rowA = s * 16 + m16;
        if (GATHER) rowA = ridx[rowA];
        size_t rowBase = (size_t)rowA * 128;
#pragma unroll
        for (int ks = 0; ks < 4; ++ks) {
            int off = ks * 32 + kg * 8;
            if (IN_BF16) {
                a[ks] = *(const short8*)(Ab16 + rowBase + off);
            } else {
                floatx4 f0 = *(const floatx4*)(Af + rowBase + off);
                floatx4 f1 = *(const floatx4*)(Af + rowBase + off + 4);
                short8 t;
                t[0] = (short)f2bf(f0[0]); t[1] = (short)f2bf(f0[1]);
                t[2] = (short)f2bf(f0[2]); t[3] = (short)f2bf(f0[3]);
                t[4] = (short)f2bf(f1[0]); t[5] = (short)f2bf(f1[1]);
                t[6] = (short)f2bf(f1[2]); t[7] = (short)f2bf(f1[3]);
                a[ks] = t;
            }
        }
    };

    short8 a0[4], a1[4];
    loadA(s0, a0);
    for (int s = s0; s < nStrips; s += stride) {
        int sn = s + stride;
        if (sn < nStrips) loadA(sn, a1);

        floatx4 acc[2];
        acc[0] = (floatx4){0.f, 0.f, 0.f, 0.f};
        acc[1] = (floatx4){0.f, 0.f, 0.f, 0.f};
#pragma unroll
        for (int ks = 0; ks < 4; ++ks) {
            acc[0] = __builtin_amdgcn_mfma_f32_16x16x32_bf16(b[ks][0], a0[ks], acc[0], 0, 0, 0);
            acc[1] = __builtin_amdgcn_mfma_f32_16x16x32_bf16(b[ks][1], a0[ks], acc[1], 0, 0, 0);
        }

        // lane holds out[row = s*16+m16][cols c0..c0+3], c0 = (2wv+j)*16 + kg*4
        size_t rbase = ((size_t)s * 16 + m16) * 128;
#pragma unroll
        for (int j = 0; j < 2; ++j) {
            int c0 = (wv * 2 + j) * 16 + kg * 4;
            if (OUT_BF16) {
                ushortx4 o;
#pragma unroll
                for (int i = 0; i < 4; ++i) o[i] = f2bf(acc[j][i] + bv[j][i]);
                *(ushortx4*)((unsigned short*)Cout + rbase + c0) = o;
            } else {
                floatx4 o;
#pragma unroll
                for (int i = 0; i < 4; ++i) o[i] = acc[j][i] + bv[j][i];
                *(floatx4*)((float*)Cout + rbase + c0) = o;
            }
        }
#pragma unroll
        for (int ks = 0; ks < 4; ++ks) a0[ks] = a1[ks];
    }
}

// ---------------------------------------------------------------------------
// Quad h-GEMM, 16 waves / 1024 threads, column-split roles:
//   w 0..3 : Ah  (nt = {2w, 2w+1}),      fp32 out (floatx4 store)
//   w 4..7 : Eh  (nt = {2(w-4), ...}),   bf16 out (ushortx4 store)
//   w 8..15: Bh+Dh (nt = w-8, both mats) -> one interleaved 16B short8 store
// Swapped-operand MFMA as in gemm128. Grid-stride over strips.
// ---------------------------------------------------------------------------
__global__ __launch_bounds__(1024) void gemm_h4(const float* __restrict__ h_cur,
                                                const unsigned short* __restrict__ WtL,
                                                const float* __restrict__ Abi,
                                                const float* __restrict__ Bbi,
                                                const float* __restrict__ Dbi,
                                                const float* __restrict__ Ebi,
                                                float* __restrict__ AhB,
                                                unsigned short* __restrict__ BD16,
                                                unsigned short* __restrict__ Eh16,
                                                int nStrips) {
    const int lane = threadIdx.x & 63;
    const int w = threadIdx.x >> 6;    // 0..15
    const int m16 = lane & 15;
    const int kg = lane >> 4;

    short8 bf[4][2];
    floatx4 bv[2];
    if (w < 8) {
        const int slot = (w < 4) ? 0 : 4;                 // A or E weights
        const float* bp = (w < 4) ? Abi : Ebi;
        const int ntb = (w & 3) * 2;
#pragma unroll
        for (int j = 0; j < 2; ++j) {
#pragma unroll
            for (int ks = 0; ks < 4; ++ks)
                bf[ks][j] = *(const short8*)(WtL + slot * 16384 +
                                             ((ntb + j) * 16 + m16) * 128 + ks * 32 + kg * 8);
            bv[j] = *(const floatx4*)(bp + (ntb + j) * 16 + kg * 4);
        }
    } else {
        const int nt = w - 8;
#pragma unroll
        for (int ks = 0; ks < 4; ++ks) {
            bf[ks][0] = *(const short8*)(WtL + 1 * 16384 + (nt * 16 + m16) * 128 + ks * 32 + kg * 8); // B
            bf[ks][1] = *(const short8*)(WtL + 3 * 16384 + (nt * 16 + m16) * 128 + ks * 32 + kg * 8); // D
        }
        bv[0] = *(const floatx4*)(Bbi + nt * 16 + kg * 4);
        bv[1] = *(const floatx4*)(Dbi + nt * 16 + kg * 4);
    }

    for (int s = blockIdx.x; s < nStrips; s += gridDim.x) {
        size_t rowBase = ((size_t)s * 16 + m16) * 128;
        short8 a[4];
#pragma unroll
        for (int ks = 0; ks < 4; ++ks) {
            int off = ks * 32 + kg * 8;
            floatx4 f0 = *(const floatx4*)(h_cur + rowBase + off);
            floatx4 f1 = *(const floatx4*)(h_cur + rowBase + off + 4);
            short8 t;
            t[0] = (short)f2bf(f0[0]); t[1] = (short)f2bf(f0[1]);
            t[2] = (short)f2bf(f0[2]); t[3] = (short)f2bf(f0[3]);
            t[4] = (short)f2bf(f1[0]); t[5] = (short)f2bf(f1[1]);
            t[6] = (short)f2bf(f1[2]); t[7] = (short)f2bf(f1[3]);
            a[ks] = t;
        }

        floatx4 acc0 = (floatx4){0.f, 0.f, 0.f, 0.f};
        floatx4 acc1 = (floatx4){0.f, 0.f, 0.f, 0.f};
#pragma unroll
        for (int ks = 0; ks < 4; ++ks) {
            acc0 = __builtin_amdgcn_mfma_f32_16x16x32_bf16(bf[ks][0], a[ks], acc0, 0, 0, 0);
            acc1 = __builtin_amdgcn_mfma_f32_16x16x32_bf16(bf[ks][1], a[ks], acc1, 0, 0, 0);
        }

        size_t r = (size_t)s * 16 + m16;
        if (w < 4) {
            const int ntb = (w & 3) * 2;
            floatx4 o0, o1;
#pragma unroll
            for (int i = 0; i < 4; ++i) { o0[i] = acc0[i] + bv[0][i]; o1[i] = acc1[i] + bv[1][i]; }
            *(floatx4*)(AhB + r * 128 + (ntb + 0) * 16 + kg * 4) = o0;
            *(floatx4*)(AhB + r * 128 + (ntb + 1) * 16 + kg * 4) = o1;
        } else if (w < 8) {
            const int ntb = (w & 3) * 2;
            ushortx4 o0, o1;
#pragma unroll
            for (int i = 0; i < 4; ++i) {
                o0[i] = f2bf(acc0[i] + bv[0][i]);
                o1[i] = f2bf(acc1[i] + bv[1][i]);
            }
            *(ushortx4*)(Eh16 + r * 128 + (ntb + 0) * 16 + kg * 4) = o0;
            *(ushortx4*)(Eh16 + r * 128 + (ntb + 1) * 16 + kg * 4) = o1;
        } else {
            const int nt = w - 8;
            short8 o;
#pragma unroll
            for (int i = 0; i < 4; ++i) {
                o[2 * i]     = (short)f2bf(acc0[i] + bv[0][i]);  // Bh even
                o[2 * i + 1] = (short)f2bf(acc1[i] + bv[1][i]);  // Dh odd
            }
            *(short8*)(BD16 + r * 256 + (nt * 16 + kg * 4) * 2) = o;
        }
    }
}

// ---------------------------------------------------------------------------
// Fused gate + CSR aggregation + node combine + BN stats.
// ---------------------------------------------------------------------------
template <int DO_E>
__global__ __launch_bounds__(256) void node_aggregate(unsigned short* __restrict__ Ce,
                                                      const unsigned short* __restrict__ BD16,
                                                      const unsigned short* __restrict__ Eh16,
                                                      const int* __restrict__ rowptr,
                                                      const int* __restrict__ sx,
                                                      const float* __restrict__ Ah,
                                                      float* __restrict__ h_new,
                                                      float* __restrict__ sums, int N) {
    const int q = threadIdx.x & 31;
    const int g = threadIdx.x >> 5;
    float hs[4] = {0.f, 0.f, 0.f, 0.f};
    float hq[4] = {0.f, 0.f, 0.f, 0.f};
    float es[4] = {0.f, 0.f, 0.f, 0.f};
    float eq[4] = {0.f, 0.f, 0.f, 0.f};
    for (int d = blockIdx.x * 8 + g; d < N; d += gridDim.x * 8) {
        int beg = rowptr[d], end = rowptr[d + 1];
        ushortx4 eh4 = *(const ushortx4*)(Eh16 + (size_t)d * 128 + q * 4);
        float ehf[4];
#pragma unroll
        for (int k = 0; k < 4; ++k) ehf[k] = bf2f(eh4[k]);
        float num[4] = {0.f, 0.f, 0.f, 0.f};
        float den[4] = {0.f, 0.f, 0.f, 0.f};
        int j = beg;
        for (; j + 1 < end; j += 2) {
            int s0 = sx[j], s1 = sx[j + 1];
            ushortx4 c0 = *(const ushortx4*)(Ce + (size_t)j * 128 + q * 4);
            ushortx4 c1 = *(const ushortx4*)(Ce + (size_t)(j + 1) * 128 + q * 4);
            short8 bd0 = *(const short8*)(BD16 + (size_t)s0 * 256 + q * 8);
            short8 bd1 = *(const short8*)(BD16 + (size_t)s1 * 256 + q * 8);
            ushortx4 o0, o1;
#pragma unroll
            for (int k = 0; k < 4; ++k) {
                float en0 = bf2f(c0[k]) + bf2f((unsigned short)bd0[2 * k + 1]) + ehf[k];
                float en1 = bf2f(c1[k]) + bf2f((unsigned short)bd1[2 * k + 1]) + ehf[k];
                if (DO_E) {
                    es[k] += en0 + en1;
                    eq[k] += en0 * en0 + en1 * en1;
                    o0[k] = f2bf(en0);
                    o1[k] = f2bf(en1);
                }
                float sg0 = 1.f / (1.f + __expf(-en0));
                float sg1 = 1.f / (1.f + __expf(-en1));
                den[k] += sg0 + sg1;
                num[k] += sg0 * bf2f((unsigned short)bd0[2 * k])
                        + sg1 * bf2f((unsigned short)bd1[2 * k]);
            }
            if (DO_E) {
                *(ushortx4*)(Ce + (size_t)j * 128 + q * 4) = o0;
                *(ushortx4*)(Ce + (size_t)(j + 1) * 128 + q * 4) = o1;
            }
        }
        if (j < end) {
            int s0 = sx[j];
            ushortx4 c0 = *(const ushortx4*)(Ce + (size_t)j * 128 + q * 4);
            short8 bd0 = *(const short8*)(BD16 + (size_t)s0 * 256 + q * 8);
            ushortx4 o0;
#pragma unroll
            for (int k = 0; k < 4; ++k) {
                float en0 = bf2f(c0[k]) + bf2f((unsigned short)bd0[2 * k + 1]) + ehf[k];
                if (DO_E) {
                    es[k] += en0;
                    eq[k] += en0 * en0;
                    o0[k] = f2bf(en0);
                }
                float sg0 = 1.f / (1.f + __expf(-en0));
                den[k] += sg0;
                num[k] += sg0 * bf2f((unsigned short)bd0[2 * k]);
            }
            if (DO_E) *(ushortx4*)(Ce + (size_t)j * 128 + q * 4) = o0;
        }
        floatx4 ah = *(const floatx4*)(Ah + (size_t)d * 128 + q * 4);
        floatx4 out;
#pragma unroll
        for (int k = 0; k < 4; ++k) {
            float v = ah[k] + num[k] / (den[k] + 1e-6f);
            out[k] = v;
            hs[k] += v;
            hq[k] += v * v;
        }
        *(floatx4*)(h_new + (size_t)d * 128 + q * 4) = out;
    }
    __shared__ float ls[512];
    ls[threadIdx.x] = 0.f;
    ls[256 + threadIdx.x] = 0.f;
    __syncthreads();
#pragma unroll
    for (int k = 0; k < 4; ++k) {
        atomicAdd(&ls[q * 4 + k], hs[k]);
        atomicAdd(&ls[128 + q * 4 + k], hq[k]);
        if (DO_E) {
            atomicAdd(&ls[256 + q * 4 + k], es[k]);
            atomicAdd(&ls[384 + q * 4 + k], eq[k]);
        }
    }
    __syncthreads();
    atomicAdd(&sums[threadIdx.x], ls[threadIdx.x]);
    if (DO_E) atomicAdd(&sums[256 + threadIdx.x], ls[256 + threadIdx.x]);
}

// ---------------------------------------------------------------------------
// Finalize BN stats -> affine coefs.
// ---------------------------------------------------------------------------
__global__ void finalize_stats(const float* __restrict__ sums,
                               const float* __restrict__ gh,
                               const float* __restrict__ bh,
                               const float* __restrict__ ge,
                               const float* __restrict__ be,
                               float* __restrict__ coef, int N, int E) {
    int c = threadIdx.x;
    if (c >= 128) return;
    float muh = sums[c] / (float)N;
    float vh = fmaxf(sums[128 + c] / (float)N - muh * muh, 0.f);
    float rsh = rsqrtf(vh + 1e-5f);
    float g = gh[c], bt = bh[c];
    coef[c] = g * rsh;
    coef[128 + c] = bt - g * rsh * muh;
    float mue = sums[256 + c] / (float)E;
    float ve = fmaxf(sums[384 + c] / (float)E - mue * mue, 0.f);
    float rse = rsqrtf(ve + 1e-5f);
    float g2 = ge[c], b2 = be[c];
    coef[256 + c] = g2 * rse;
    coef[384 + c] = b2 - g2 * rse * mue;
}

// ---------------------------------------------------------------------------
// h residual update.
// ---------------------------------------------------------------------------
__global__ __launch_bounds__(256) void h_update(const float* __restrict__ h_new,
                                                const float* __restrict__ coef,
                                                float* __restrict__ h_cur,
                                                float* __restrict__ out, int N) {
    const int c = threadIdx.x & 127;
    float sa = coef[c], sb = coef[128 + c];
    int total = N * 128;
    for (int i = blockIdx.x * blockDim.x + threadIdx.x; i < total; i += gridDim.x * blockDim.x) {
        float v = h_new[i] * sa + sb;
        v = v > 0.f ? v : 0.f;
        float h = h_cur[i] + v;
        h_cur[i] = h;
        if (out) out[i] = h;
    }
}

// ---------------------------------------------------------------------------
// e residual update, vectorized: e_cur += relu(BN(e_new)), 8 bf16/thread/iter.
// ---------------------------------------------------------------------------
__global__ __launch_bounds__(256) void e_update(const unsigned short* __restrict__ e_new,
                                                const float* __restrict__ coef,
                                                unsigned short* __restrict__ e_cur, int E) {
    int total8 = E * 16;  // groups of 8 shorts
    for (int idx = blockIdx.x * blockDim.x + threadIdx.x; idx < total8;
         idx += gridDim.x * blockDim.x) {
        int c8 = (idx & 15) * 8;
        short8 en = *(const short8*)(e_new + (size_t)idx * 8);
        short8 ec = *(const short8*)(e_cur + (size_t)idx * 8);
        floatx4 sa0 = *(const floatx4*)(coef + 256 + c8);
        floatx4 sa1 = *(const floatx4*)(coef + 256 + c8 + 4);
        floatx4 sb0 = *(const floatx4*)(coef + 384 + c8);
        floatx4 sb1 = *(const floatx4*)(coef + 384 + c8 + 4);
        short8 r;
#pragma unroll
        for (int k = 0; k < 8; ++k) {
            float sa = (k < 4) ? sa0[k] : sa1[k - 4];
            float sb = (k < 4) ? sb0[k] : sb1[k - 4];
            float v = bf2f((unsigned short)en[k]) * sa + sb;
            v = v > 0.f ? v : 0.f;
            r[k] = (short)f2bf(bf2f((unsigned short)ec[k]) + v);
        }
        *(short8*)(e_cur + (size_t)idx * 8) = r;
    }
}

extern "C" void kernel_launch(void* const* d_in, const int* in_sizes, int n_in,
                              void* d_out, int out_size, void* d_ws, size_t ws_size,
                              hipStream_t stream) {
    const int N = 20000, E = 256000, L = 4;

    const float* h_in = (const float*)d_in[0];
    const float* e_in = (const float*)d_in[1];
    const int* src = (const int*)d_in[2];
    const int* dst = (const int*)d_in[3];
    const float* Wemb_h = (const float*)d_in[4];
    const float* bemb_h = (const float*)d_in[5];
    const float* Wemb_e = (const float*)d_in[6];
    const float* bemb_e = (const float*)d_in[7];
    const float* Aw = (const float*)d_in[8];
    const float* Abi = (const float*)d_in[9];
    const float* Bw = (const float*)d_in[10];
    const float* Bbi = (const float*)d_in[11];
    const float* Cw = (const float*)d_in[12];
    const float* Cbi = (const float*)d_in[13];
    const float* Dw = (const float*)d_in[14];
    const float* Dbi = (const float*)d_in[15];
    const float* Ew = (const float*)d_in[16];
    const float* Ebi = (const float*)d_in[17];
    const float* gh = (const float*)d_in[18];
    const float* bh = (const float*)d_in[19];
    const float* ge = (const float*)d_in[20];
    const float* be = (const float*)d_in[21];

    char* p = (char*)d_ws;
    auto carve = [&](size_t bytes) {
        void* r = (void*)p;
        p += ((bytes + 255) & ~(size_t)255);
        return r;
    };
    unsigned short* Wt = (unsigned short*)carve((size_t)22 * 16384 * 2);
    float* h_cur = (float*)carve((size_t)N * 128 * 4);
    unsigned short* e_cur = (unsigned short*)carve((size_t)E * 128 * 2);   // CSR order
    unsigned short* e_new = (unsigned short*)carve((size_t)E * 128 * 2);   // Ce then e_new, CSR
    float* AhB = (float*)carve((size_t)N * 128 * 4);
    unsigned short* BD16 = (unsigned short*)carve((size_t)N * 256 * 2);    // Bh/Dh interleaved
    unsigned short* Eh16 = (unsigned short*)carve((size_t)N * 128 * 2);
    float* h_newB = (float*)carve((size_t)N * 128 * 4);
    float* sums = (float*)carve(4 * 128 * 4);
    float* coef = (float*)carve(4 * 128 * 4);
    int* deg = (int*)carve((size_t)N * 4);
    int* rowptr = (int*)carve((size_t)(N + 1) * 4);
    int* cursor = (int*)carve((size_t)N * 4);
    int* eix = (int*)carve((size_t)E * 4);
    int* sx = (int*)carve((size_t)E * 4);

    // ---- CSR build ----
    hipMemsetAsync(deg, 0, (size_t)N * 4, stream);
    deg_count<<<(E + 255) / 256, 256, 0, stream>>>(dst, deg, E);
    scan_rowptr<<<1, 1024, 0, stream>>>(deg, rowptr, cursor, N);
    scatter_edges<<<(E + 255) / 256, 256, 0, stream>>>(src, dst, cursor, eix, sx, E);

    // weights -> transposed bf16 layout
    transpose_w<<<(22 * 16384 + 255) / 256, 256, 0, stream>>>(Wemb_h, Wemb_e, Aw, Bw, Cw, Dw, Ew, Wt);

    // input embeddings: h normal; e gathered into CSR order (bf16 out)
    gemm128<0, 0, 0><<<1024, 256, 0, stream>>>(h_in, nullptr, Wt + 0 * 16384, bemb_h, h_cur, N / 16);
    gemm128<0, 1, 1><<<1024, 256, 0, stream>>>(e_in, eix, Wt + 1 * 16384, bemb_e, e_cur, E / 16);

    for (int l = 0; l < L; ++l) {
        int last = (l == L - 1);
        hipMemsetAsync(sums, 0, 4 * 128 * 4, stream);
        const unsigned short* WtL = Wt + (size_t)(2 + l * 5) * 16384;
        gemm_h4<<<250, 1024, 0, stream>>>(h_cur, WtL, Abi + l * 128, Bbi + l * 128,
                                          Dbi + l * 128, Ebi + l * 128, AhB, BD16, Eh16,
                                          N / 16);
        // Ce = e_cur @ Cw + Cb   (pure streaming GEMM, bf16 -> bf16)
        gemm128<1, 1, 0><<<1024, 256, 0, stream>>>(e_cur, nullptr, WtL + 2 * 16384, Cbi + l * 128,
                                                   e_new, E / 16);
        if (!last)
            node_aggregate<1><<<1250, 256, 0, stream>>>(e_new, BD16, Eh16, rowptr, sx, AhB,
                                                        h_newB, sums, N);
        else
            node_aggregate<0><<<1250, 256, 0, stream>>>(e_new, BD16, Eh16, rowptr, sx, AhB,
                                                        h_newB, sums, N);
        finalize_stats<<<1, 128, 0, stream>>>(sums, gh + l * 128, bh + l * 128, ge + l * 128,
                                              be + l * 128, coef, N, E);
        h_update<<<512, 256, 0, stream>>>(h_newB, coef, h_cur, last ? (float*)d_out : nullptr, N);
        if (!last) e_update<<<2048, 256, 0, stream>>>(e_new, coef, e_cur, E);
    }
}

// Round 2
// 967.359 us; speedup vs baseline: 1.1549x; 1.0971x over previous
//
#include <hip/hip_runtime.h>
#include <hip/hip_bf16.h>

typedef __attribute__((ext_vector_type(8))) short short8;
typedef __attribute__((ext_vector_type(4))) float floatx4;
typedef __attribute__((ext_vector_type(4))) unsigned short ushortx4;

typedef __attribute__((address_space(3))) unsigned int lds_u32;
typedef __attribute__((address_space(1))) const unsigned int g_u32;

__device__ __forceinline__ float bf2f(unsigned short u) {
    union { float f; unsigned int i; } v; v.i = ((unsigned int)u) << 16; return v.f;
}
__device__ __forceinline__ unsigned short f2bf(float f) {
    union { float f; unsigned int i; } v; v.f = f;
    unsigned int r = v.i + 0x7fffu + ((v.i >> 16) & 1u);
    return (unsigned short)(r >> 16);
}

// ---------------------------------------------------------------------------
// CSR build: degree histogram -> chunked block scan -> scatter.
// ---------------------------------------------------------------------------
__global__ void deg_count(const int* __restrict__ dst, int* __restrict__ deg, int E) {
    int i = blockIdx.x * 256 + threadIdx.x;
    if (i < E) atomicAdd(&deg[dst[i]], 1);
}

__global__ __launch_bounds__(1024) void scan_rowptr(const int* __restrict__ deg,
                                                    int* __restrict__ rowptr,
                                                    int* __restrict__ cursor, int N) {
    const int CH = 20;  // 1024*20 = 20480 >= N
    __shared__ int buf[1024];
    int t = threadIdx.x;
    int base = t * CH;
    int local[CH];
    int tot = 0;
#pragma unroll
    for (int k = 0; k < CH; ++k) {
        int i = base + k;
        int v = (i < N) ? deg[i] : 0;
        local[k] = tot;
        tot += v;
    }
    buf[t] = tot;
    __syncthreads();
    for (int off = 1; off < 1024; off <<= 1) {
        int x = (t >= off) ? buf[t - off] : 0;
        __syncthreads();
        buf[t] += x;
        __syncthreads();
    }
    int excl = buf[t] - tot;
#pragma unroll
    for (int k = 0; k < CH; ++k) {
        int i = base + k;
        if (i < N) { rowptr[i] = excl + local[k]; cursor[i] = excl + local[k]; }
    }
    if (t == 1023) rowptr[N] = buf[1023];
}

__global__ void scatter_edges(const int* __restrict__ src, const int* __restrict__ dst,
                              int* __restrict__ cursor, int* __restrict__ eix,
                              int* __restrict__ sx, int E) {
    int i = blockIdx.x * 256 + threadIdx.x;
    if (i >= E) return;
    int d = dst[i];
    int pos = atomicAdd(&cursor[d], 1);
    eix[pos] = i;
    sx[pos] = src[i];
}

// ---------------------------------------------------------------------------
// Weight pre-transpose + bf16 convert: Wt[slot][n*128+k] = bf16(W[slot][k*128+n])
// ---------------------------------------------------------------------------
__global__ void transpose_w(const float* __restrict__ Wh,
                            const float* __restrict__ We,
                            const float* __restrict__ Aw,
                            const float* __restrict__ Bw,
                            const float* __restrict__ Cw,
                            const float* __restrict__ Dw,
                            const float* __restrict__ Ew,
                            unsigned short* __restrict__ Wt) {
    int i = blockIdx.x * 256 + threadIdx.x;
    const int total = 22 * 16384;
    if (i >= total) return;
    int slot = i >> 14;
    int r = i & 16383;
    int n = r >> 7;
    int k = r & 127;
    const float* srcp;
    if (slot == 0) srcp = Wh;
    else if (slot == 1) srcp = We;
    else {
        int t = slot - 2;
        int l = t / 5, w = t % 5;
        const float* bases[5] = {Aw, Bw, Cw, Dw, Ew};
        srcp = bases[w] + l * 16384;
    }
    Wt[i] = f2bf(srcp[k * 128 + n]);
}

// ---------------------------------------------------------------------------
// LDS-staged streaming GEMM: C[M,128] = A[M,128]@W + bias.
// 64-row tiles staged via global_load_lds (async DMA -> deep MLP), double
// buffered, m97-style drain (__syncthreads per tile). LDS XOR-swizzled
// (byte ^= (row&7)<<4 for bf16, (row&3)<<5 for f32): linear DMA dest +
// inverse-swizzled GLOBAL source + swizzled ds_read (rule: both-sides).
// Column-split: wave wv owns cols [wv*32, wv*32+32). Swapped-operand MFMA:
// lane holds 4 contiguous output cols of one row -> 8B/16B stores.
// GATHER: per-lane DMA source row remapped through ridx (CSR gather, free).
// ---------------------------------------------------------------------------
template <int IN_F32, int OUT_BF16, int GATHER>
__global__ __launch_bounds__(256) void gemm_lds(const void* __restrict__ Ain,
                                                const int* __restrict__ ridx,
                                                const unsigned short* __restrict__ Wt,
                                                const float* __restrict__ bias,
                                                void* __restrict__ Cout,
                                                int nTiles, int Mrows) {
    constexpr int ROWB = IN_F32 ? 512 : 256;     // bytes per row
    constexpr int RSH = IN_F32 ? 9 : 8;
    constexpr int TILEB = 64 * ROWB;             // 32KB / 16KB
    constexpr int PERW = TILEB / 4;              // bytes staged per wave
    constexpr int ROUNDS = PERW / 1024;          // gl_lds insts per wave
    __shared__ unsigned char smem[2][TILEB];

    const int lane = threadIdx.x & 63;
    const int wv = threadIdx.x >> 6;
    const int m16 = lane & 15;
    const int kg = lane >> 4;

    // B fragments: wave's 2 nt-blocks, 8 x short8 = 32 VGPRs.
    short8 b[4][2];
#pragma unroll
    for (int j = 0; j < 2; ++j)
#pragma unroll
        for (int ks = 0; ks < 4; ++ks)
            b[ks][j] = *(const short8*)(Wt + ((wv * 2 + j) * 16 + m16) * 128 + ks * 32 + kg * 8);
    floatx4 bv[2];
#pragma unroll
    for (int j = 0; j < 2; ++j)
        bv[j] = *(const floatx4*)(bias + (wv * 2 + j) * 16 + kg * 4);

    const unsigned char* Ab = (const unsigned char*)Ain;

    int t0 = blockIdx.x;
    if (t0 >= nTiles) return;

    auto stage = [&](int bufsel, int t) {
#pragma unroll
        for (int r = 0; r < ROUNDS; ++r) {
            int d = wv * PERW + r * 1024 + lane * 16;   // linear dest byte in tile
            int row = d >> RSH;
            int scol;
            if (IN_F32)
                scol = (d ^ ((row & 3) << 5)) & (ROWB - 1);
            else
                scol = (d ^ ((row & 7) << 4)) & (ROWB - 1);
            int grow = t * 64 + row;
            grow = grow < Mrows ? grow : Mrows - 1;     // clamp tail (h path)
            if (GATHER) grow = ridx[grow];
            const unsigned char* gp = Ab + (size_t)grow * ROWB + scol;
            unsigned char* lp = &smem[bufsel][wv * PERW + r * 1024];  // wave-uniform
            __builtin_amdgcn_global_load_lds((g_u32*)gp, (lds_u32*)lp, 16, 0, 0);
        }
    };

    int cur = 0;
    stage(0, t0);
    __syncthreads();

    for (int t = t0; t < nTiles; t += gridDim.x) {
        int tn = t + gridDim.x;
        if (tn < nTiles) stage(cur ^ 1, tn);   // prefetch overlaps compute

        const unsigned char* sb = smem[cur];
#pragma unroll
        for (int st = 0; st < 4; ++st) {
            short8 a[4];
#pragma unroll
            for (int ks = 0; ks < 4; ++ks) {
                if (IN_F32) {
                    int aoff = (st * 16 + m16) * 512 + ks * 128 + kg * 32;
                    aoff ^= (m16 & 3) << 5;
                    floatx4 f0 = *(const floatx4*)(sb + aoff);
                    floatx4 f1 = *(const floatx4*)(sb + aoff + 16);
                    short8 tt;
                    tt[0] = (short)f2bf(f0[0]); tt[1] = (short)f2bf(f0[1]);
                    tt[2] = (short)f2bf(f0[2]); tt[3] = (short)f2bf(f0[3]);
                    tt[4] = (short)f2bf(f1[0]); tt[5] = (short)f2bf(f1[1]);
                    tt[6] = (short)f2bf(f1[2]); tt[7] = (short)f2bf(f1[3]);
                    a[ks] = tt;
                } else {
                    int aoff = (st * 16 + m16) * 256 + ks * 64 + kg * 16;
                    aoff ^= (m16 & 7) << 4;
                    a[ks] = *(const short8*)(sb + aoff);
                }
            }
            floatx4 acc0 = (floatx4){0.f, 0.f, 0.f, 0.f};
            floatx4 acc1 = (floatx4){0.f, 0.f, 0.f, 0.f};
#pragma unroll
            for (int ks = 0; ks < 4; ++ks) {
                acc0 = __builtin_amdgcn_mfma_f32_16x16x32_bf16(b[ks][0], a[ks], acc0, 0, 0, 0);
                acc1 = __builtin_amdgcn_mfma_f32_16x16x32_bf16(b[ks][1], a[ks], acc1, 0, 0, 0);
            }
            // lane holds out[row][c..c+3], row = t*64+st*16+m16, c = (2wv+j)*16+kg*4
            size_t row = (size_t)t * 64 + st * 16 + m16;
#pragma unroll
            for (int j = 0; j < 2; ++j) {
                int c0 = (wv * 2 + j) * 16 + kg * 4;
                floatx4 accj = j ? acc1 : acc0;
                if (OUT_BF16) {
                    ushortx4 o;
#pragma unroll
                    for (int i = 0; i < 4; ++i) o[i] = f2bf(accj[i] + bv[j][i]);
                    *(ushortx4*)((unsigned short*)Cout + row * 128 + c0) = o;
                } else {
                    floatx4 o;
#pragma unroll
                    for (int i = 0; i < 4; ++i) o[i] = accj[i] + bv[j][i];
                    *(floatx4*)((float*)Cout + row * 128 + c0) = o;
                }
            }
        }
        __syncthreads();   // drains DMA for next buf + orders LDS reuse
        cur ^= 1;
    }
}

// ---------------------------------------------------------------------------
// Quad h-GEMM, 16 waves / 1024 threads, column-split roles:
//   w 0..3 : Ah  (fp32 out), w 4..7 : Eh (bf16 out),
//   w 8..15: Bh+Dh (nt = w-8) -> one interleaved 16B short8 store.
// ---------------------------------------------------------------------------
__global__ __launch_bounds__(1024) void gemm_h4(const float* __restrict__ h_cur,
                                                const unsigned short* __restrict__ WtL,
                                                const float* __restrict__ Abi,
                                                const float* __restrict__ Bbi,
                                                const float* __restrict__ Dbi,
                                                const float* __restrict__ Ebi,
                                                float* __restrict__ AhB,
                                                unsigned short* __restrict__ BD16,
                                                unsigned short* __restrict__ Eh16,
                                                int nStrips) {
    const int lane = threadIdx.x & 63;
    const int w = threadIdx.x >> 6;    // 0..15
    const int m16 = lane & 15;
    const int kg = lane >> 4;

    short8 bf[4][2];
    floatx4 bv[2];
    if (w < 8) {
        const int slot = (w < 4) ? 0 : 4;                 // A or E weights
        const float* bp = (w < 4) ? Abi : Ebi;
        const int ntb = (w & 3) * 2;
#pragma unroll
        for (int j = 0; j < 2; ++j) {
#pragma unroll
            for (int ks = 0; ks < 4; ++ks)
                bf[ks][j] = *(const short8*)(WtL + slot * 16384 +
                                             ((ntb + j) * 16 + m16) * 128 + ks * 32 + kg * 8);
            bv[j] = *(const floatx4*)(bp + (ntb + j) * 16 + kg * 4);
        }
    } else {
        const int nt = w - 8;
#pragma unroll
        for (int ks = 0; ks < 4; ++ks) {
            bf[ks][0] = *(const short8*)(WtL + 1 * 16384 + (nt * 16 + m16) * 128 + ks * 32 + kg * 8); // B
            bf[ks][1] = *(const short8*)(WtL + 3 * 16384 + (nt * 16 + m16) * 128 + ks * 32 + kg * 8); // D
        }
        bv[0] = *(const floatx4*)(Bbi + nt * 16 + kg * 4);
        bv[1] = *(const floatx4*)(Dbi + nt * 16 + kg * 4);
    }

    for (int s = blockIdx.x; s < nStrips; s += gridDim.x) {
        size_t rowBase = ((size_t)s * 16 + m16) * 128;
        short8 a[4];
#pragma unroll
        for (int ks = 0; ks < 4; ++ks) {
            int off = ks * 32 + kg * 8;
            floatx4 f0 = *(const floatx4*)(h_cur + rowBase + off);
            floatx4 f1 = *(const floatx4*)(h_cur + rowBase + off + 4);
            short8 t;
            t[0] = (short)f2bf(f0[0]); t[1] = (short)f2bf(f0[1]);
            t[2] = (short)f2bf(f0[2]); t[3] = (short)f2bf(f0[3]);
            t[4] = (short)f2bf(f1[0]); t[5] = (short)f2bf(f1[1]);
            t[6] = (short)f2bf(f1[2]); t[7] = (short)f2bf(f1[3]);
            a[ks] = t;
        }

        floatx4 acc0 = (floatx4){0.f, 0.f, 0.f, 0.f};
        floatx4 acc1 = (floatx4){0.f, 0.f, 0.f, 0.f};
#pragma unroll
        for (int ks = 0; ks < 4; ++ks) {
            acc0 = __builtin_amdgcn_mfma_f32_16x16x32_bf16(bf[ks][0], a[ks], acc0, 0, 0, 0);
            acc1 = __builtin_amdgcn_mfma_f32_16x16x32_bf16(bf[ks][1], a[ks], acc1, 0, 0, 0);
        }

        size_t r = (size_t)s * 16 + m16;
        if (w < 4) {
            const int ntb = (w & 3) * 2;
            floatx4 o0, o1;
#pragma unroll
            for (int i = 0; i < 4; ++i) { o0[i] = acc0[i] + bv[0][i]; o1[i] = acc1[i] + bv[1][i]; }
            *(floatx4*)(AhB + r * 128 + (ntb + 0) * 16 + kg * 4) = o0;
            *(floatx4*)(AhB + r * 128 + (ntb + 1) * 16 + kg * 4) = o1;
        } else if (w < 8) {
            const int ntb = (w & 3) * 2;
            ushortx4 o0, o1;
#pragma unroll
            for (int i = 0; i < 4; ++i) {
                o0[i] = f2bf(acc0[i] + bv[0][i]);
                o1[i] = f2bf(acc1[i] + bv[1][i]);
            }
            *(ushortx4*)(Eh16 + r * 128 + (ntb + 0) * 16 + kg * 4) = o0;
            *(ushortx4*)(Eh16 + r * 128 + (ntb + 1) * 16 + kg * 4) = o1;
        } else {
            const int nt = w - 8;
            short8 o;
#pragma unroll
            for (int i = 0; i < 4; ++i) {
                o[2 * i]     = (short)f2bf(acc0[i] + bv[0][i]);  // Bh even
                o[2 * i + 1] = (short)f2bf(acc1[i] + bv[1][i]);  // Dh odd
            }
            *(short8*)(BD16 + r * 256 + (nt * 16 + kg * 4) * 2) = o;
        }
    }
}

// ---------------------------------------------------------------------------
// Fused gate + CSR aggregation + node combine + BN stats.
// ---------------------------------------------------------------------------
template <int DO_E>
__global__ __launch_bounds__(256) void node_aggregate(unsigned short* __restrict__ Ce,
                                                      const unsigned short* __restrict__ BD16,
                                                      const unsigned short* __restrict__ Eh16,
                                                      const int* __restrict__ rowptr,
                                                      const int* __restrict__ sx,
                                                      const float* __restrict__ Ah,
                                                      float* __restrict__ h_new,
                                                      float* __restrict__ sums, int N) {
    const int q = threadIdx.x & 31;
    const int g = threadIdx.x >> 5;
    float hs[4] = {0.f, 0.f, 0.f, 0.f};
    float hq[4] = {0.f, 0.f, 0.f, 0.f};
    float es[4] = {0.f, 0.f, 0.f, 0.f};
    float eq[4] = {0.f, 0.f, 0.f, 0.f};
    for (int d = blockIdx.x * 8 + g; d < N; d += gridDim.x * 8) {
        int beg = rowptr[d], end = rowptr[d + 1];
        ushortx4 eh4 = *(const ushortx4*)(Eh16 + (size_t)d * 128 + q * 4);
        float ehf[4];
#pragma unroll
        for (int k = 0; k < 4; ++k) ehf[k] = bf2f(eh4[k]);
        float num[4] = {0.f, 0.f, 0.f, 0.f};
        float den[4] = {0.f, 0.f, 0.f, 0.f};
        int j = beg;
        for (; j + 1 < end; j += 2) {
            int s0 = sx[j], s1 = sx[j + 1];
            ushortx4 c0 = *(const ushortx4*)(Ce + (size_t)j * 128 + q * 4);
            ushortx4 c1 = *(const ushortx4*)(Ce + (size_t)(j + 1) * 128 + q * 4);
            short8 bd0 = *(const short8*)(BD16 + (size_t)s0 * 256 + q * 8);
            short8 bd1 = *(const short8*)(BD16 + (size_t)s1 * 256 + q * 8);
            ushortx4 o0, o1;
#pragma unroll
            for (int k = 0; k < 4; ++k) {
                float en0 = bf2f(c0[k]) + bf2f((unsigned short)bd0[2 * k + 1]) + ehf[k];
                float en1 = bf2f(c1[k]) + bf2f((unsigned short)bd1[2 * k + 1]) + ehf[k];
                if (DO_E) {
                    es[k] += en0 + en1;
                    eq[k] += en0 * en0 + en1 * en1;
                    o0[k] = f2bf(en0);
                    o1[k] = f2bf(en1);
                }
                float sg0 = 1.f / (1.f + __expf(-en0));
                float sg1 = 1.f / (1.f + __expf(-en1));
                den[k] += sg0 + sg1;
                num[k] += sg0 * bf2f((unsigned short)bd0[2 * k])
                        + sg1 * bf2f((unsigned short)bd1[2 * k]);
            }
            if (DO_E) {
                *(ushortx4*)(Ce + (size_t)j * 128 + q * 4) = o0;
                *(ushortx4*)(Ce + (size_t)(j + 1) * 128 + q * 4) = o1;
            }
        }
        if (j < end) {
            int s0 = sx[j];
            ushortx4 c0 = *(const ushortx4*)(Ce + (size_t)j * 128 + q * 4);
            short8 bd0 = *(const short8*)(BD16 + (size_t)s0 * 256 + q * 8);
            ushortx4 o0;
#pragma unroll
            for (int k = 0; k < 4; ++k) {
                float en0 = bf2f(c0[k]) + bf2f((unsigned short)bd0[2 * k + 1]) + ehf[k];
                if (DO_E) {
                    es[k] += en0;
                    eq[k] += en0 * en0;
                    o0[k] = f2bf(en0);
                }
                float sg0 = 1.f / (1.f + __expf(-en0));
                den[k] += sg0;
                num[k] += sg0 * bf2f((unsigned short)bd0[2 * k]);
            }
            if (DO_E) *(ushortx4*)(Ce + (size_t)j * 128 + q * 4) = o0;
        }
        floatx4 ah = *(const floatx4*)(Ah + (size_t)d * 128 + q * 4);
        floatx4 out;
#pragma unroll
        for (int k = 0; k < 4; ++k) {
            float v = ah[k] + num[k] / (den[k] + 1e-6f);
            out[k] = v;
            hs[k] += v;
            hq[k] += v * v;
        }
        *(floatx4*)(h_new + (size_t)d * 128 + q * 4) = out;
    }
    __shared__ float ls[512];
    ls[threadIdx.x] = 0.f;
    ls[256 + threadIdx.x] = 0.f;
    __syncthreads();
#pragma unroll
    for (int k = 0; k < 4; ++k) {
        atomicAdd(&ls[q * 4 + k], hs[k]);
        atomicAdd(&ls[128 + q * 4 + k], hq[k]);
        if (DO_E) {
            atomicAdd(&ls[256 + q * 4 + k], es[k]);
            atomicAdd(&ls[384 + q * 4 + k], eq[k]);
        }
    }
    __syncthreads();
    atomicAdd(&sums[threadIdx.x], ls[threadIdx.x]);
    if (DO_E) atomicAdd(&sums[256 + threadIdx.x], ls[256 + threadIdx.x]);
}

// ---------------------------------------------------------------------------
// Finalize BN stats -> affine coefs.
// ---------------------------------------------------------------------------
__global__ void finalize_stats(const float* __restrict__ sums,
                               const float* __restrict__ gh,
                               const float* __restrict__ bh,
                               const float* __restrict__ ge,
                               const float* __restrict__ be,
                               float* __restrict__ coef, int N, int E) {
    int c = threadIdx.x;
    if (c >= 128) return;
    float muh = sums[c] / (float)N;
    float vh = fmaxf(sums[128 + c] / (float)N - muh * muh, 0.f);
    float rsh = rsqrtf(vh + 1e-5f);
    float g = gh[c], bt = bh[c];
    coef[c] = g * rsh;
    coef[128 + c] = bt - g * rsh * muh;
    float mue = sums[256 + c] / (float)E;
    float ve = fmaxf(sums[384 + c] / (float)E - mue * mue, 0.f);
    float rse = rsqrtf(ve + 1e-5f);
    float g2 = ge[c], b2 = be[c];
    coef[256 + c] = g2 * rse;
    coef[384 + c] = b2 - g2 * rse * mue;
}

// ---------------------------------------------------------------------------
// h residual update.
// ---------------------------------------------------------------------------
__global__ __launch_bounds__(256) void h_update(const float* __restrict__ h_new,
                                                const float* __restrict__ coef,
                                                float* __restrict__ h_cur,
                                                float* __restrict__ out, int N) {
    const int c = threadIdx.x & 127;
    float sa = coef[c], sb = coef[128 + c];
    int total = N * 128;
    for (int i = blockIdx.x * blockDim.x + threadIdx.x; i < total; i += gridDim.x * blockDim.x) {
        float v = h_new[i] * sa + sb;
        v = v > 0.f ? v : 0.f;
        float h = h_cur[i] + v;
        h_cur[i] = h;
        if (out) out[i] = h;
    }
}

// ---------------------------------------------------------------------------
// e residual update, vectorized: e_cur += relu(BN(e_new)), 8 bf16/thread/iter.
// ---------------------------------------------------------------------------
__global__ __launch_bounds__(256) void e_update(const unsigned short* __restrict__ e_new,
                                                const float* __restrict__ coef,
                                                unsigned short* __restrict__ e_cur, int E) {
    int total8 = E * 16;  // groups of 8 shorts
    for (int idx = blockIdx.x * blockDim.x + threadIdx.x; idx < total8;
         idx += gridDim.x * blockDim.x) {
        int c8 = (idx & 15) * 8;
        short8 en = *(const short8*)(e_new + (size_t)idx * 8);
        short8 ec = *(const short8*)(e_cur + (size_t)idx * 8);
        floatx4 sa0 = *(const floatx4*)(coef + 256 + c8);
        floatx4 sa1 = *(const floatx4*)(coef + 256 + c8 + 4);
        floatx4 sb0 = *(const floatx4*)(coef + 384 + c8);
        floatx4 sb1 = *(const floatx4*)(coef + 384 + c8 + 4);
        short8 r;
#pragma unroll
        for (int k = 0; k < 8; ++k) {
            float sa = (k < 4) ? sa0[k] : sa1[k - 4];
            float sb = (k < 4) ? sb0[k] : sb1[k - 4];
            float v = bf2f((unsigned short)en[k]) * sa + sb;
            v = v > 0.f ? v : 0.f;
            r[k] = (short)f2bf(bf2f((unsigned short)ec[k]) + v);
        }
        *(short8*)(e_cur + (size_t)idx * 8) = r;
    }
}

extern "C" void kernel_launch(void* const* d_in, const int* in_sizes, int n_in,
                              void* d_out, int out_size, void* d_ws, size_t ws_size,
                              hipStream_t stream) {
    const int N = 20000, E = 256000, L = 4;
    const int NPAD = 20032;  // 313 tiles of 64 rows

    const float* h_in = (const float*)d_in[0];
    const float* e_in = (const float*)d_in[1];
    const int* src = (const int*)d_in[2];
    const int* dst = (const int*)d_in[3];
    const float* Wemb_h = (const float*)d_in[4];
    const float* bemb_h = (const float*)d_in[5];
    const float* Wemb_e = (const float*)d_in[6];
    const float* bemb_e = (const float*)d_in[7];
    const float* Aw = (const float*)d_in[8];
    const float* Abi = (const float*)d_in[9];
    const float* Bw = (const float*)d_in[10];
    const float* Bbi = (const float*)d_in[11];
    const float* Cw = (const float*)d_in[12];
    const float* Cbi = (const float*)d_in[13];
    const float* Dw = (const float*)d_in[14];
    const float* Dbi = (const float*)d_in[15];
    const float* Ew = (const float*)d_in[16];
    const float* Ebi = (const float*)d_in[17];
    const float* gh = (const float*)d_in[18];
    const float* bh = (const float*)d_in[19];
    const float* ge = (const float*)d_in[20];
    const float* be = (const float*)d_in[21];

    char* p = (char*)d_ws;
    auto carve = [&](size_t bytes) {
        void* r = (void*)p;
        p += ((bytes + 255) & ~(size_t)255);
        return r;
    };
    unsigned short* Wt = (unsigned short*)carve((size_t)22 * 16384 * 2);
    float* h_cur = (float*)carve((size_t)NPAD * 128 * 4);                 // padded rows
    unsigned short* e_cur = (unsigned short*)carve((size_t)E * 128 * 2);  // CSR order
    unsigned short* e_new = (unsigned short*)carve((size_t)E * 128 * 2);  // Ce then e_new, CSR
    float* AhB = (float*)carve((size_t)N * 128 * 4);
    unsigned short* BD16 = (unsigned short*)carve((size_t)N * 256 * 2);   // Bh/Dh interleaved
    unsigned short* Eh16 = (unsigned short*)carve((size_t)N * 128 * 2);
    float* h_newB = (float*)carve((size_t)N * 128 * 4);
    float* sums = (float*)carve(4 * 128 * 4);
    float* coef = (float*)carve(4 * 128 * 4);
    int* deg = (int*)carve((size_t)N * 4);
    int* rowptr = (int*)carve((size_t)(N + 1) * 4);
    int* cursor = (int*)carve((size_t)N * 4);
    int* eix = (int*)carve((size_t)E * 4);
    int* sx = (int*)carve((size_t)E * 4);

    // ---- CSR build ----
    hipMemsetAsync(deg, 0, (size_t)N * 4, stream);
    deg_count<<<(E + 255) / 256, 256, 0, stream>>>(dst, deg, E);
    scan_rowptr<<<1, 1024, 0, stream>>>(deg, rowptr, cursor, N);
    scatter_edges<<<(E + 255) / 256, 256, 0, stream>>>(src, dst, cursor, eix, sx, E);

    // weights -> transposed bf16 layout
    transpose_w<<<(22 * 16384 + 255) / 256, 256, 0, stream>>>(Wemb_h, Wemb_e, Aw, Bw, Cw, Dw, Ew, Wt);

    // input embeddings (LDS-staged): h normal; e gathered into CSR order via DMA src
    gemm_lds<1, 0, 0><<<313, 256, 0, stream>>>(h_in, nullptr, Wt + 0 * 16384, bemb_h,
                                               h_cur, 313, N);
    gemm_lds<1, 1, 1><<<1024, 256, 0, stream>>>(e_in, eix, Wt + 1 * 16384, bemb_e,
                                                e_cur, E / 64, E);

    for (int l = 0; l < L; ++l) {
        int last = (l == L - 1);
        hipMemsetAsync(sums, 0, 4 * 128 * 4, stream);
        const unsigned short* WtL = Wt + (size_t)(2 + l * 5) * 16384;
        gemm_h4<<<250, 1024, 0, stream>>>(h_cur, WtL, Abi + l * 128, Bbi + l * 128,
                                          Dbi + l * 128, Ebi + l * 128, AhB, BD16, Eh16,
                                          N / 16);
        // Ce = e_cur @ Cw + Cb   (LDS-staged streaming GEMM, bf16 -> bf16)
        gemm_lds<0, 1, 0><<<1024, 256, 0, stream>>>(e_cur, nullptr, WtL + 2 * 16384,
                                                    Cbi + l * 128, e_new, E / 64, E);
        if (!last)
            node_aggregate<1><<<1250, 256, 0, stream>>>(e_new, BD16, Eh16, rowptr, sx, AhB,
                                                        h_newB, sums, N);
        else
            node_aggregate<0><<<1250, 256, 0, stream>>>(e_new, BD16, Eh16, rowptr, sx, AhB,
                                                        h_newB, sums, N);
        finalize_stats<<<1, 128, 0, stream>>>(sums, gh + l * 128, bh + l * 128, ge + l * 128,
                                              be + l * 128, coef, N, E);
        h_update<<<512, 256, 0, stream>>>(h_newB, coef, h_cur, last ? (float*)d_out : nullptr, N);
        if (!last) e_update<<<2048, 256, 0, stream>>>(e_new, coef, e_cur, E);
    }
}